// Round 17
// baseline (213.138 us; speedup 1.0000x reference)
//
#include <hip/hip_runtime.h>
#include <cstdint>
#include <cstddef>

#define EPSC 1e-7f
#define EPS9 1e-9f
#define K4PI2 0.40528473456935108577f
#define NTOPK 10
#define GX 16
#define GY 16
#define NCELL (GX * GY)
#define POOLCAP 2048

__device__ __forceinline__ bool mask_at(const unsigned char* mb, int i, int wide) {
    if (wide) return reinterpret_cast<const unsigned int*>(mb)[i] != 0u;
    return mb[i] != 0;
}

__device__ __forceinline__ unsigned long long shfl_xor_u64(unsigned long long v, int off) {
    int lo = __shfl_xor((int)(unsigned)(v & 0xFFFFFFFFull), off);
    int hi = __shfl_xor((int)(unsigned)(v >> 32), off);
    return ((unsigned long long)(unsigned)hi << 32) | (unsigned)lo;
}

__device__ __forceinline__ unsigned lane_rank(unsigned long long ball) {
    return __builtin_amdgcn_mbcnt_hi((unsigned)(ball >> 32),
           __builtin_amdgcn_mbcnt_lo((unsigned)(ball & 0xFFFFFFFFull), 0u));
}

__device__ __forceinline__ float ciou_clip(float x1a, float y1a, float x2a, float y2a,
                                           float w1h1, float atan1,
                                           float4 pb, float at2) {
    float w2 = pb.z - pb.x, h2 = pb.w - pb.y + EPSC;
    float iw = fmaxf(fminf(x2a, pb.z) - fmaxf(x1a, pb.x), 0.f);
    float ih = fmaxf(fminf(y2a, pb.w) - fmaxf(y1a, pb.y), 0.f);
    float inter = iw * ih;
    float uni = w1h1 + w2 * h2 - inter;
    float iou = inter / (uni + EPSC);
    float cw = fmaxf(x2a, pb.z) - fminf(x1a, pb.x);
    float ch = fmaxf(y2a, pb.w) - fminf(y1a, pb.y);
    float c2 = cw * cw + ch * ch + EPSC;
    float dx = pb.x + pb.z - x1a - x2a;
    float dy = pb.y + pb.w - y1a - y2a;
    float rho2 = (dx * dx + dy * dy) * 0.25f;
    float dat = at2 - atan1;
    float vv = K4PI2 * dat * dat;
    float aa = vv / (vv - iou + (1.f + EPSC));
    return fmaxf(iou - (rho2 / c2 + vv * aa), 0.f);
}

// K00: fast streaming zero
__global__ void k_zero(float4* __restrict__ p, int n4) {
    int i = blockIdx.x * 256 + threadIdx.x;
    if (i < n4) p[i] = make_float4(0.f, 0.f, 0.f, 0.f);
}

#define CELLOF(px, py, cx, cy) \
    int cx = min(GX - 1, max(0, (int)floorf((px - ox) * ivx))); \
    int cy = min(GY - 1, max(0, (int)floorf((py - oy) * ivy)));

// K0: fused mask-layout detect + spatial binning (single 1024-thread block).
// reps>1 = diagnostic amplification (same work repeated).
__global__ __launch_bounds__(1024) void k_prep(
    const unsigned char* __restrict__ mask, int nmask, int* __restrict__ mode,
    const float* __restrict__ anc, int A,
    int* __restrict__ cell_start, int* __restrict__ binned, float* __restrict__ gp,
    int reps)
{
    __shared__ int h[NCELL];
    __shared__ int cs[NCELL + 1];
    __shared__ int cur[NCELL];
    __shared__ float rmnx[16], rmny[16], rmxx[16], rmxy[16];
    __shared__ float s_gp[4];
    __shared__ int bad;

    int tid = threadIdx.x;
    int lane = tid & 63, wid = tid >> 6;
    const float2* an2 = reinterpret_cast<const float2*>(anc);
    const float4* an4 = reinterpret_cast<const float4*>(anc);
    int aMain = A & ~4095;           // 1024 threads x 4 anchors per iteration

    for (int rep = 0; rep < reps; ++rep) {
        if (tid == 0) bad = 0;
        if (tid < NCELL) h[tid] = 0;
        __syncthreads();

        const unsigned int* mw = reinterpret_cast<const unsigned int*>(mask);
        int nw = nmask >> 2;
        for (int i = tid; i < nw; i += 1024) {
            unsigned int v = mw[i];
            if (v != 0u && v != 1u && v != 0x3f800000u) atomicOr(&bad, 1);
        }

        // pass 0: min/max (4 anchors/thread/iter)
        float mnx = 3e38f, mny = 3e38f, mxx = -3e38f, mxy = -3e38f;
        for (int base = 0; base < aMain; base += 4096) {
            int q = (base >> 1) + tid * 2;
            float4 p01 = an4[q], p23 = an4[q + 1];
            mnx = fminf(mnx, fminf(fminf(p01.x, p01.z), fminf(p23.x, p23.z)));
            mny = fminf(mny, fminf(fminf(p01.y, p01.w), fminf(p23.y, p23.w)));
            mxx = fmaxf(mxx, fmaxf(fmaxf(p01.x, p01.z), fmaxf(p23.x, p23.z)));
            mxy = fmaxf(mxy, fmaxf(fmaxf(p01.y, p01.w), fmaxf(p23.y, p23.w)));
        }
        for (int i = aMain + tid; i < A; i += 1024) {
            float2 p = an2[i];
            mnx = fminf(mnx, p.x); mny = fminf(mny, p.y);
            mxx = fmaxf(mxx, p.x); mxy = fmaxf(mxy, p.y);
        }
#pragma unroll
        for (int off = 32; off; off >>= 1) {
            mnx = fminf(mnx, __shfl_xor(mnx, off));
            mny = fminf(mny, __shfl_xor(mny, off));
            mxx = fmaxf(mxx, __shfl_xor(mxx, off));
            mxy = fmaxf(mxy, __shfl_xor(mxy, off));
        }
        if (lane == 0) { rmnx[wid] = mnx; rmny[wid] = mny; rmxx[wid] = mxx; rmxy[wid] = mxy; }
        __syncthreads();
        if (tid == 0) {
            mode[0] = bad ? 0 : 1;
            float a = 3e38f, b2 = 3e38f, c = -3e38f, d = -3e38f;
            for (int i = 0; i < 16; ++i) {
                a = fminf(a, rmnx[i]); b2 = fminf(b2, rmny[i]);
                c = fmaxf(c, rmxx[i]); d = fmaxf(d, rmxy[i]);
            }
            float rx = fmaxf(c - a, 1e-6f), ry = fmaxf(d - b2, 1e-6f);
            s_gp[0] = a; s_gp[1] = b2;
            s_gp[2] = (float)GX / rx; s_gp[3] = (float)GY / ry;
            gp[0] = s_gp[0]; gp[1] = s_gp[1]; gp[2] = s_gp[2]; gp[3] = s_gp[3];
        }
        __syncthreads();
        float ox = s_gp[0], oy = s_gp[1], ivx = s_gp[2], ivy = s_gp[3];

        // pass 1: histogram (4 anchors/thread/iter)
        for (int base = 0; base < aMain; base += 4096) {
            int q = (base >> 1) + tid * 2;
            float4 p01 = an4[q], p23 = an4[q + 1];
            { CELLOF(p01.x, p01.y, cx, cy) atomicAdd(&h[cy * GX + cx], 1); }
            { CELLOF(p01.z, p01.w, cx, cy) atomicAdd(&h[cy * GX + cx], 1); }
            { CELLOF(p23.x, p23.y, cx, cy) atomicAdd(&h[cy * GX + cx], 1); }
            { CELLOF(p23.z, p23.w, cx, cy) atomicAdd(&h[cy * GX + cx], 1); }
        }
        for (int i = aMain + tid; i < A; i += 1024) {
            float2 p = an2[i];
            CELLOF(p.x, p.y, cx, cy)
            atomicAdd(&h[cy * GX + cx], 1);
        }
        __syncthreads();
        if (wid == 0) {
            int base = 0;
            for (int ch = 0; ch < NCELL / 64; ++ch) {
                int v = h[ch * 64 + lane];
                int inc = v;
                for (int off = 1; off < 64; off <<= 1) {
                    int u = __shfl_up(inc, off);
                    if (lane >= off) inc += u;
                }
                cs[ch * 64 + lane] = base + inc - v;
                base += __shfl(inc, 63);
            }
            if (lane == 0) cs[NCELL] = base;
        }
        __syncthreads();
        if (tid <= NCELL) cell_start[tid] = cs[tid];
        if (tid < NCELL) cur[tid] = cs[tid];
        __syncthreads();
        // pass 2: scatter (4 anchors/thread/iter)
        for (int base = 0; base < aMain; base += 4096) {
            int a0 = base + tid * 4;
            int q = a0 >> 1;
            float4 p01 = an4[q], p23 = an4[q + 1];
            { CELLOF(p01.x, p01.y, cx, cy) binned[atomicAdd(&cur[cy * GX + cx], 1)] = a0; }
            { CELLOF(p01.z, p01.w, cx, cy) binned[atomicAdd(&cur[cy * GX + cx], 1)] = a0 + 1; }
            { CELLOF(p23.x, p23.y, cx, cy) binned[atomicAdd(&cur[cy * GX + cx], 1)] = a0 + 2; }
            { CELLOF(p23.z, p23.w, cx, cy) binned[atomicAdd(&cur[cy * GX + cx], 1)] = a0 + 3; }
        }
        for (int i = aMain + tid; i < A; i += 1024) {
            float2 p = an2[i];
            CELLOF(p.x, p.y, cx, cy)
            binned[atomicAdd(&cur[cy * GX + cx], 1)] = i;
        }
        __syncthreads();
    }
}

#define INTEST(ap) ((ap.x - x1a > EPS9) & (ap.y - y1a > EPS9) & \
                    (x2a - ap.x > EPS9) & (y2a - ap.y > EPS9))

// exact single-wave fallback scan (overflow path; dead for this input distribution)
__device__ void fb_scan(
    int lane, int A, int C, float x1a, float y1a, float x2a, float y2a,
    float w1h1, float atan1, int lbl,
    int cx0, int cx1, int cy0, int cy1,
    const float2* an2, const float4* pb4, const float* ps,
    const int* cell_start, const int* binned,
    int* count, int* win_idx, float* win_al, int* win_fl,
    size_t bA, int base_o)
{
    unsigned long long tv[NTOPK];
#pragma unroll
    for (int j = 0; j < NTOPK; ++j) tv[j] = 0;
    int pcnt = 0;
    for (int cy = cy0; cy <= cy1; ++cy) {
        int s = cell_start[cy * GX + cx0], e = cell_start[cy * GX + cx1 + 1];
        for (int i = s + lane; i < e; i += 64) {
            int a = binned[i];
            float2 ap = an2[a];
            bool in = INTEST(ap);
            if (in) {
                float4 pb = pb4[a];
                float w2 = pb.z - pb.x, h2 = pb.w - pb.y + EPSC;
                float at2 = atanf(w2 / h2);
                float ovl = ciou_clip(x1a, y1a, x2a, y2a, w1h1, atan1, pb, at2);
                float sc = (lbl >= 0) ? ps[(size_t)a * C + lbl] : 0.f;
                float o2 = ovl * ovl;
                float val = sqrtf(sc) * (o2 * o2 * o2);
                pcnt += (val > 0.f) ? 1 : 0;
                unsigned long long kk =
                    ((unsigned long long)__float_as_uint(val) << 32) | (unsigned)(~(unsigned)a);
                if (kk > tv[NTOPK - 1]) {
                    tv[NTOPK - 1] = kk;
#pragma unroll
                    for (int j = NTOPK - 1; j > 0; --j)
                        if (tv[j] > tv[j - 1]) {
                            unsigned long long t = tv[j]; tv[j] = tv[j - 1]; tv[j - 1] = t;
                        }
                }
            }
        }
    }
#pragma unroll
    for (int off = 32; off; off >>= 1) pcnt += __shfl_xor(pcnt, off);
    int rp = pcnt < NTOPK ? pcnt : NTOPK;
    for (int k = 0; k < rp; ++k) {
        unsigned long long head = tv[0];
        unsigned long long best = head;
#pragma unroll
        for (int off = 32; off; off >>= 1) {
            unsigned long long o = shfl_xor_u64(best, off);
            if (o > best) best = o;
        }
        if (head == best && head != 0ull) {
            int a = (int)(~(unsigned)(best & 0xFFFFFFFFull));
            int o = base_o + k;
            win_idx[o] = a; win_al[o] = __uint_as_float((unsigned)(best >> 32)); win_fl[o] = 1;
            atomicAdd(&count[bA + a], 1);
#pragma unroll
            for (int j = 0; j < NTOPK - 1; ++j) tv[j] = tv[j + 1];
            tv[NTOPK - 1] = 0;
        }
    }
    if (rp < NTOPK) {
        int iters = (A + 63 - lane) / 64;
        int zp = 0;
        for (int k = rp; k < NTOPK; ++k) {
            unsigned zprop = 0xFFFFFFFFu;
            while (zp < iters) {
                int a = lane + zp * 64;
                float2 ap = an2[a];
                if (!INTEST(ap)) { zprop = (unsigned)a; break; }
                ++zp;
            }
            unsigned cprop = 0xFFFFFFFFu;
#pragma unroll
            for (int j = 0; j < NTOPK; ++j) {
                unsigned long long kk = tv[j];
                if (kk != 0ull && kk < (1ull << 32)) {
                    unsigned idx2 = ~(unsigned)kk;
                    if (idx2 < cprop) cprop = idx2;
                }
            }
            unsigned prop = zprop < cprop ? zprop : cprop;
            unsigned bm_ = prop;
#pragma unroll
            for (int off = 32; off; off >>= 1) {
                unsigned o = (unsigned)__shfl_xor((int)bm_, off);
                if (o < bm_) bm_ = o;
            }
            if (bm_ != 0xFFFFFFFFu) {
                if (cprop == bm_ && cprop < zprop) {
                    int o = base_o + k;
                    win_idx[o] = (int)bm_; win_al[o] = 0.f; win_fl[o] = 1;
                    atomicAdd(&count[bA + bm_], 1);
                    unsigned long long wkk = (unsigned long long)(unsigned)(~bm_);
#pragma unroll
                    for (int j = 0; j < NTOPK; ++j) if (tv[j] == wkk) tv[j] = 0;
                } else if (zprop == bm_ && zprop < cprop) {
                    ++zp;
                }
            }
        }
    }
}

// K2: one 256-thread block per (b,m). Parallel strip-table setup; 4-wide batched
// PREDICATED gathers; ballot-aggregated LDS pool; single-wave top-10 tournament
// == lax.top_k (value desc, idx asc) via u64 key (val_bits<<32)|~idx.
// Grid may be k*BM (diagnostic copies map to same rows, scratch outputs).
__global__ __launch_bounds__(256) void k_sel(
    const float* __restrict__ pd_scores, const float* __restrict__ pd_bboxes,
    const float* __restrict__ anc, const float* __restrict__ gt_labels,
    const float* __restrict__ gt_bboxes, const unsigned char* __restrict__ mask_gt,
    const int* __restrict__ mode, const int* __restrict__ cell_start,
    const int* __restrict__ binned, const float* __restrict__ gp,
    int* __restrict__ count, int* __restrict__ win_idx, float* __restrict__ win_al,
    int* __restrict__ win_fl,
    int A, int C, int M, int B, int BM)
{
    __shared__ unsigned long long pool[POOLCAP];
    __shared__ int sP[GY + 1];
    __shared__ int sB[GY];
    __shared__ int s_n, s_ovf;

    int rid = blockIdx.x;
    while (rid >= BM) rid -= BM;
    int b = rid % B, m = rid / B;        // XCD swizzle: same-b rows on one XCD (B%8==0)
    int row = b * M + m;
    if (!mask_at(mask_gt, row, mode[0])) return;   // win_fl pre-zeroed -> no claims
    int tid = threadIdx.x;
    int lane = tid & 63, wid = tid >> 6;

    float4 g = reinterpret_cast<const float4*>(gt_bboxes)[row];
    float x1a = g.x, y1a = g.y, x2a = g.z, y2a = g.w;
    float w1 = x2a - x1a, h1 = y2a - y1a + EPSC;
    float w1h1 = w1 * h1;
    float atan1 = atanf(w1 / h1);
    int lbl = (int)gt_labels[row];

    float ox = gp[0], oy = gp[1], ivx = gp[2], ivy = gp[3];
    // identical expressions to k_prep; monotone -> cannot miss any in-box anchor
    int cx0 = min(GX - 1, max(0, (int)floorf((x1a - ox) * ivx)));
    int cx1 = min(GX - 1, max(0, (int)floorf((x2a - ox) * ivx)));
    int cy0 = min(GY - 1, max(0, (int)floorf((y1a - oy) * ivy)));
    int cy1 = min(GY - 1, max(0, (int)floorf((y2a - oy) * ivy)));
    int ns = cy1 - cy0 + 1;

    // parallel strip table: 16-lane loads + shfl prefix (was a tid0-serial loop)
    if (wid == 0) {
        int len = 0, S = 0;
        if (lane < ns) {
            int cbase = (cy0 + lane) * GX;
            S = cell_start[cbase + cx0];
            len = cell_start[cbase + cx1 + 1] - S;
        }
        int inc = len;
#pragma unroll
        for (int off = 1; off < 16; off <<= 1) {
            int u = __shfl_up(inc, off);
            if (lane >= off) inc += u;
        }
        if (lane < ns) { sP[lane] = inc - len; sB[lane] = S - (inc - len); }
        if (lane == ns - 1) sP[ns] = inc;
        if (lane == 0) { s_n = 0; s_ovf = 0; }
    }
    __syncthreads();
    int L = sP[ns];

    const float2* an2 = reinterpret_cast<const float2*>(anc);
    const float4* pb4 = reinterpret_cast<const float4*>(pd_bboxes + (size_t)b * A * 4);
    const float*  ps  = pd_scores + (size_t)b * A * C;
    size_t bA = (size_t)b * A;
    int base_o = row * NTOPK;

    // Phase A: 4-wide batched candidate processing (predicated pb/ps gathers)
    int sptr = 0;
    for (int f0 = tid; f0 < L; f0 += 1024) {
        int f1 = f0 + 256, f2 = f0 + 512, f3 = f0 + 768;
        bool o1 = f1 < L, o2 = f2 < L, o3 = f3 < L;
        while (f0 >= sP[sptr + 1]) ++sptr;
        int sl0 = sB[sptr] + f0;
        int sp = sptr;
        if (o1) { while (f1 >= sP[sp + 1]) ++sp; }
        int sl1 = sB[sp] + f1;
        if (o2) { while (f2 >= sP[sp + 1]) ++sp; }
        int sl2 = sB[sp] + f2;
        if (o3) { while (f3 >= sP[sp + 1]) ++sp; }
        int sl3 = sB[sp] + f3;

        int a0 = binned[sl0];
        int a1 = o1 ? binned[sl1] : 0;
        int a2 = o2 ? binned[sl2] : 0;
        int a3 = o3 ? binned[sl3] : 0;
        float2 ap0 = an2[a0], ap1 = an2[a1], ap2 = an2[a2], ap3 = an2[a3];
        bool in0 = INTEST(ap0);
        bool in1 = o1 & INTEST(ap1);
        bool in2 = o2 & INTEST(ap2);
        bool in3 = o3 & INTEST(ap3);

        float4 pb0, pb1, pb2, pb3;
        float sc0 = 0.f, sc1 = 0.f, sc2 = 0.f, sc3 = 0.f;
        if (in0) { pb0 = pb4[a0]; if (lbl >= 0) sc0 = ps[(size_t)a0 * C + lbl]; }
        if (in1) { pb1 = pb4[a1]; if (lbl >= 0) sc1 = ps[(size_t)a1 * C + lbl]; }
        if (in2) { pb2 = pb4[a2]; if (lbl >= 0) sc2 = ps[(size_t)a2 * C + lbl]; }
        if (in3) { pb3 = pb4[a3]; if (lbl >= 0) sc3 = ps[(size_t)a3 * C + lbl]; }

#define PROC(ink, ak, pbk, sck) { \
        unsigned long long key = 0; \
        if (ink) { \
            float w2 = pbk.z - pbk.x, h2 = pbk.w - pbk.y + EPSC; \
            float at2 = atanf(w2 / h2); \
            float ovl = ciou_clip(x1a, y1a, x2a, y2a, w1h1, atan1, pbk, at2); \
            float o2v = ovl * ovl; \
            float val = sqrtf(sck) * (o2v * o2v * o2v); \
            key = ((unsigned long long)__float_as_uint(val) << 32) | (unsigned)(~(unsigned)ak); \
        } \
        unsigned long long ball = __ballot(ink); \
        if (ball) { \
            int bs = 0; \
            if (lane == 0) bs = atomicAdd(&s_n, __popcll(ball)); \
            bs = __shfl(bs, 0); \
            if (ink) { \
                int pos = bs + (int)lane_rank(ball); \
                if (pos < POOLCAP) pool[pos] = key; else s_ovf = 1; \
            } \
        } }
        PROC(in0, a0, pb0, sc0)
        PROC(in1, a1, pb1, sc1)
        PROC(in2, a2, pb2, sc2)
        PROC(in3, a3, pb3, sc3)
#undef PROC
    }
    __syncthreads();
    if (s_ovf || s_n > POOLCAP) {        // dead for this input (in-box <= ~1100 < 2048)
        if (wid == 0)
            fb_scan(lane, A, C, x1a, y1a, x2a, y2a, w1h1, atan1, lbl,
                    cx0, cx1, cy0, cy1, an2, pb4, ps, cell_start, binned,
                    count, win_idx, win_al, win_fl, bA, base_o);
        return;
    }
    if (wid != 0) return;                // Phase B is single-wave, barrier-free

    int n = s_n;
    unsigned long long tv[NTOPK];
#pragma unroll
    for (int j = 0; j < NTOPK; ++j) tv[j] = 0;
    int pcnt = 0;
    for (int i = lane; i < n; i += 64) {
        unsigned long long kk = pool[i];
        pcnt += (kk >> 32) ? 1 : 0;
        if (kk > tv[NTOPK - 1]) {
            tv[NTOPK - 1] = kk;
#pragma unroll
            for (int j = NTOPK - 1; j > 0; --j)
                if (tv[j] > tv[j - 1]) { unsigned long long t = tv[j]; tv[j] = tv[j - 1]; tv[j - 1] = t; }
        }
    }
#pragma unroll
    for (int off = 32; off; off >>= 1) pcnt += __shfl_xor(pcnt, off);
    int p = pcnt;
    int rp = p < NTOPK ? p : NTOPK;

    // 3a: positive rounds — register head + wave-max butterfly, winner pops
    for (int k = 0; k < rp; ++k) {
        unsigned long long head = tv[0];
        unsigned long long best = head;
#pragma unroll
        for (int off = 32; off; off >>= 1) {
            unsigned long long o = shfl_xor_u64(best, off);
            if (o > best) best = o;
        }
        if (head == best && head != 0ull) {      // unique owner (keys unique by idx)
            int a = (int)(~(unsigned)(best & 0xFFFFFFFFull));
            int o = base_o + k;
            win_idx[o] = a;
            win_al[o]  = __uint_as_float((unsigned)(best >> 32));
            win_fl[o]  = 1;
            atomicAdd(&count[bA + a], 1);
#pragma unroll
            for (int j = 0; j < NTOPK - 1; ++j) tv[j] = tv[j + 1];
            tv[NTOPK - 1] = 0;
        }
    }

    // 3b (rare: p < 10): fill with smallest-index zero-val anchors; in-box zero-vals claim.
    if (rp < NTOPK) {
        int iters = (A + 63 - lane) / 64;
        int zp = 0;
        for (int k = rp; k < NTOPK; ++k) {
            unsigned zprop = 0xFFFFFFFFu;
            while (zp < iters) {
                int a = lane + zp * 64;
                float2 ap = an2[a];
                if (!INTEST(ap)) { zprop = (unsigned)a; break; }
                ++zp;
            }
            unsigned cprop = 0xFFFFFFFFu;
#pragma unroll
            for (int j = 0; j < NTOPK; ++j) {
                unsigned long long kk = tv[j];
                if (kk != 0ull && kk < (1ull << 32)) {
                    unsigned idx2 = ~(unsigned)kk;
                    if (idx2 < cprop) cprop = idx2;
                }
            }
            unsigned prop = zprop < cprop ? zprop : cprop;
            unsigned bm_ = prop;
#pragma unroll
            for (int off = 32; off; off >>= 1) {
                unsigned o = (unsigned)__shfl_xor((int)bm_, off);
                if (o < bm_) bm_ = o;
            }
            if (bm_ != 0xFFFFFFFFu) {
                if (cprop == bm_ && cprop < zprop) {
                    int o = base_o + k;
                    win_idx[o] = (int)bm_; win_al[o] = 0.f; win_fl[o] = 1;
                    atomicAdd(&count[bA + bm_], 1);
                    unsigned long long wkk = (unsigned long long)(unsigned)(~bm_);
#pragma unroll
                    for (int j = 0; j < NTOPK; ++j) if (tv[j] == wkk) tv[j] = 0;
                } else if (zprop == bm_ && zprop < cprop) {
                    ++zp;
                }
            }
        }
    }
}

// K3: claim resolution + fused pos_al/pos_ov atomicMax (winner CIoU recomputed)
__global__ void k_resolve(
    const float* __restrict__ pd_scores, const float* __restrict__ pd_bboxes,
    const float* __restrict__ anc, const float* __restrict__ gt_labels,
    const float* __restrict__ gt_bboxes, const unsigned char* __restrict__ mask_gt,
    const int* __restrict__ mode,
    const int* __restrict__ count, const int* __restrict__ win_idx,
    const float* __restrict__ win_al, const int* __restrict__ win_fl,
    int* __restrict__ claim_m, float* __restrict__ claim_al,
    float* __restrict__ pos_al, float* __restrict__ pos_ov,
    int A, int C, int M, int total)
{
    int t = blockIdx.x * 256 + threadIdx.x;
    if (t >= total) return;
    int bm = t / NTOPK;
    int b = bm / M, m = bm % M;
    if (!win_fl[t]) return;
    int a = win_idx[t];
    size_t ba = (size_t)b * A + a;
    int cnt = count[ba];
    float al, ov; int mm_out;
    if (cnt == 1) {
        mm_out = m; al = win_al[t];
        float4 gg = reinterpret_cast<const float4*>(gt_bboxes)[b * M + m];
        float w1 = gg.z - gg.x, h1 = gg.w - gg.y + EPSC;
        float4 pb = reinterpret_cast<const float4*>(pd_bboxes)[ba];
        float w2 = pb.z - pb.x, h2p = pb.w - pb.y + EPSC;
        ov = ciou_clip(gg.x, gg.y, gg.z, gg.w, w1 * h1, atanf(w1 / h1), pb, atanf(w2 / h2p));
    } else {
        int wide = mode[0];
        float4 pb = reinterpret_cast<const float4*>(pd_bboxes)[ba];
        float2 ap = reinterpret_cast<const float2*>(anc)[a];
        float w2 = pb.z - pb.x, h2p = pb.w - pb.y + EPSC;
        float at2 = atanf(w2 / h2p);
        float best_ov = -1.f; int best_m = 0, best_valid = 0;
        for (int mm = 0; mm < M; ++mm) {
            float4 gg = reinterpret_cast<const float4*>(gt_bboxes)[b * M + mm];
            bool in = (ap.x - gg.x > EPS9) && (ap.y - gg.y > EPS9) &&
                      (gg.z - ap.x > EPS9) && (gg.w - ap.y > EPS9);
            bool valid = in && mask_at(mask_gt, b * M + mm, wide);
            float ovv = 0.f;
            if (valid) {
                float w1 = gg.z - gg.x, h1 = gg.w - gg.y + EPSC;
                ovv = ciou_clip(gg.x, gg.y, gg.z, gg.w, w1 * h1, atanf(w1 / h1), pb, at2);
            }
            if (ovv > best_ov) { best_ov = ovv; best_m = mm; best_valid = valid ? 1 : 0; }
        }
        int lb = (int)gt_labels[b * M + best_m];
        float sc = (best_valid && lb >= 0) ? pd_scores[ba * C + lb] : 0.f;
        float o2 = best_ov * best_ov;
        mm_out = best_m; al = sqrtf(sc) * (o2 * o2 * o2); ov = best_ov;
    }
    claim_m[ba]  = mm_out;
    claim_al[ba] = al;
    atomicMax((unsigned int*)&pos_al[b * M + mm_out], __float_as_uint(al));
    atomicMax((unsigned int*)&pos_ov[b * M + mm_out], __float_as_uint(ov));
}

// K4: per-anchor bb/fg + scattered single-score write (out_ts pre-zeroed by k_zero)
__global__ __launch_bounds__(256) void k_final_small(
    const int* __restrict__ count, const int* __restrict__ claim_m,
    const float* __restrict__ claim_al,
    const float* __restrict__ pos_al, const float* __restrict__ pos_ov,
    const float* __restrict__ gt_labels, const float* __restrict__ gt_bboxes,
    float* __restrict__ out_bb, float* __restrict__ out_ts, float* __restrict__ out_fg,
    int A, int M, int C, int BA)
{
    int ba = blockIdx.x * 256 + threadIdx.x;
    if (ba >= BA) return;
    int b = ba / A;
    int cnt = count[ba];
    int m = (cnt > 0) ? claim_m[ba] : 0;       // background -> gt 0 (reference semantics)
    float4 g = reinterpret_cast<const float4*>(gt_bboxes)[b * M + m];
    reinterpret_cast<float4*>(out_bb)[ba] = g;
    out_fg[ba] = (cnt > 0) ? 1.f : 0.f;
    if (cnt > 0) {
        int lb = max((int)gt_labels[b * M + m], 0);
        float nv = claim_al[ba] * pos_ov[b * M + m] / (pos_al[b * M + m] + EPS9);
        out_ts[(size_t)ba * C + lb] = nv;      // sparse scatter (~15K total)
    }
}

extern "C" void kernel_launch(void* const* d_in, const int* in_sizes, int n_in,
                              void* d_out, int out_size, void* d_ws, size_t ws_size,
                              hipStream_t stream) {
    const float* pd_scores = (const float*)d_in[0];
    const float* pd_bboxes = (const float*)d_in[1];
    const float* anc       = (const float*)d_in[2];
    const float* gt_labels = (const float*)d_in[3];
    const float* gt_bboxes = (const float*)d_in[4];
    const unsigned char* mask_gt = (const unsigned char*)d_in[5];

    int A  = in_sizes[2] / 2;
    int BA = in_sizes[1] / 4;
    int B  = BA / A;
    int C  = in_sizes[0] / BA;
    int M  = in_sizes[3] / B;
    int BM = B * M;

    char* w = (char*)d_ws;
    auto alloc = [&](size_t bytes) { char* p = w; w += ((bytes + 255) / 256) * 256; return p; };
    int*   mode       = (int*)  alloc(256);
    char*  zero_beg   = w;
    int*   count      = (int*)  alloc((size_t)BA * 4);
    float* pos_al     = (float*)alloc((size_t)BM * 4);
    float* pos_ov     = (float*)alloc((size_t)BM * 4);
    int*   win_fl     = (int*)  alloc((size_t)BM * NTOPK * 4);
    char*  zero_end   = w;
    int*   claim_m    = (int*)  alloc((size_t)BA * 4);
    float* claim_al   = (float*)alloc((size_t)BA * 4);
    int*   win_idx    = (int*)  alloc((size_t)BM * NTOPK * 4);
    float* win_al     = (float*)alloc((size_t)BM * NTOPK * 4);
    int*   cell_start = (int*)  alloc((size_t)(NCELL + 1) * 4);
    int*   binned     = (int*)  alloc((size_t)A * 4);
    float* gp         = (float*)alloc(256);
    // diagnostic scratch (never read; outputs identical per copy -> deterministic)
    int*   count_d    = (int*)  alloc((size_t)BA * 4);
    int*   win_fl_d   = (int*)  alloc((size_t)BM * NTOPK * 4);
    int*   win_idx_d  = (int*)  alloc((size_t)BM * NTOPK * 4);
    float* win_al_d   = (float*)alloc((size_t)BM * NTOPK * 4);
    int*   cs_d       = (int*)  alloc((size_t)(NCELL + 1) * 4);
    int*   binned_d   = (int*)  alloc((size_t)A * 4);
    float* gp_d       = (float*)alloc(256);
    int*   mode_d     = (int*)  alloc(256);

    float* out_bb = (float*)d_out;
    float* out_ts = out_bb + (size_t)BA * 4;
    float* out_fg = out_ts + (size_t)BA * C;

    int n4ws = (int)((size_t)(zero_end - zero_beg) / 16);
    k_zero<<<(n4ws + 255) / 256, 256, 0, stream>>>((float4*)zero_beg, n4ws);
    int n4ts = (int)((size_t)BA * C / 4);
    k_zero<<<(n4ts + 255) / 256, 256, 0, stream>>>((float4*)out_ts, n4ts);

    k_prep<<<1, 1024, 0, stream>>>(mask_gt, BM, mode, anc, A, cell_start, binned, gp, 1);
    k_sel<<<BM, 256, 0, stream>>>(pd_scores, pd_bboxes, anc, gt_labels, gt_bboxes, mask_gt,
                                  mode, cell_start, binned, gp,
                                  count, win_idx, win_al, win_fl, A, C, M, B, BM);
    int nclaims = BM * NTOPK;
    k_resolve<<<(nclaims + 255) / 256, 256, 0, stream>>>(
        pd_scores, pd_bboxes, anc, gt_labels, gt_bboxes, mask_gt, mode,
        count, win_idx, win_al, win_fl, claim_m, claim_al, pos_al, pos_ov, A, C, M, nclaims);
    int gBA = (BA + 255) / 256;
    k_final_small<<<gBA, 256, 0, stream>>>(count, claim_m, claim_al, pos_al, pos_ov,
                                           gt_labels, gt_bboxes, out_bb, out_ts, out_fg,
                                           A, M, C, BA);

    // ---- diagnostics (scratch-only; amplified past the ~52us profiler cutoff) ----
    k_sel<<<3 * BM, 256, 0, stream>>>(pd_scores, pd_bboxes, anc, gt_labels, gt_bboxes, mask_gt,
                                      mode, cell_start, binned, gp,
                                      count_d, win_idx_d, win_al_d, win_fl_d, A, C, M, B, BM);
    k_prep<<<1, 1024, 0, stream>>>(mask_gt, BM, mode_d, anc, A, cs_d, binned_d, gp_d, 8);
}

// Round 18
// 82.274 us; speedup vs baseline: 2.5906x; 2.5906x over previous
//
#include <hip/hip_runtime.h>
#include <cstdint>
#include <cstddef>

#define EPSC 1e-7f
#define EPS9 1e-9f
#define K4PI2 0.40528473456935108577f
#define NTOPK 10
#define GX 16
#define GY 16
#define NCELL (GX * GY)
#define POOLCAP 2048

__device__ __forceinline__ bool mask_at(const unsigned char* mb, int i, int wide) {
    if (wide) return reinterpret_cast<const unsigned int*>(mb)[i] != 0u;
    return mb[i] != 0;
}

__device__ __forceinline__ unsigned long long shfl_xor_u64(unsigned long long v, int off) {
    int lo = __shfl_xor((int)(unsigned)(v & 0xFFFFFFFFull), off);
    int hi = __shfl_xor((int)(unsigned)(v >> 32), off);
    return ((unsigned long long)(unsigned)hi << 32) | (unsigned)lo;
}

__device__ __forceinline__ unsigned lane_rank(unsigned long long ball) {
    return __builtin_amdgcn_mbcnt_hi((unsigned)(ball >> 32),
           __builtin_amdgcn_mbcnt_lo((unsigned)(ball & 0xFFFFFFFFull), 0u));
}

__device__ __forceinline__ float ciou_clip(float x1a, float y1a, float x2a, float y2a,
                                           float w1h1, float atan1,
                                           float4 pb, float at2) {
    float w2 = pb.z - pb.x, h2 = pb.w - pb.y + EPSC;
    float iw = fmaxf(fminf(x2a, pb.z) - fmaxf(x1a, pb.x), 0.f);
    float ih = fmaxf(fminf(y2a, pb.w) - fmaxf(y1a, pb.y), 0.f);
    float inter = iw * ih;
    float uni = w1h1 + w2 * h2 - inter;
    float iou = inter / (uni + EPSC);
    float cw = fmaxf(x2a, pb.z) - fminf(x1a, pb.x);
    float ch = fmaxf(y2a, pb.w) - fminf(y1a, pb.y);
    float c2 = cw * cw + ch * ch + EPSC;
    float dx = pb.x + pb.z - x1a - x2a;
    float dy = pb.y + pb.w - y1a - y2a;
    float rho2 = (dx * dx + dy * dy) * 0.25f;
    float dat = at2 - atan1;
    float vv = K4PI2 * dat * dat;
    float aa = vv / (vv - iou + (1.f + EPSC));
    return fmaxf(iou - (rho2 / c2 + vv * aa), 0.f);
}

#define CELLOF(px, py, cx, cy) \
    int cx = min(GX - 1, max(0, (int)floorf((px - ox) * ivx))); \
    int cy = min(GY - 1, max(0, (int)floorf((py - oy) * ivy)));

// K0: block 0 = mask-detect + spatial binning (single-CU, ~9us);
// blocks >= 1 = grid-stride zero of {ws span, out_ts} (~14us chip-wide).
// Disjoint data -> safe fusion; prep hides under the zero.
__global__ __launch_bounds__(1024) void k_prep_zero(
    const unsigned char* __restrict__ mask, int nmask, int* __restrict__ mode,
    const float* __restrict__ anc, int A,
    int* __restrict__ cell_start, int* __restrict__ binned, float* __restrict__ gp,
    float4* __restrict__ z0, int n0, float4* __restrict__ z1, int n1)
{
    int tid = threadIdx.x;
    if (blockIdx.x != 0) {
        int nblk = gridDim.x - 1;
        int gt0 = (blockIdx.x - 1) * 1024 + tid;
        int stride = nblk * 1024;
        float4 zv = make_float4(0.f, 0.f, 0.f, 0.f);
        for (int i = gt0; i < n0; i += stride) z0[i] = zv;
        for (int i = gt0; i < n1; i += stride) z1[i] = zv;
        return;
    }

    __shared__ int h[NCELL];
    __shared__ int cs[NCELL + 1];
    __shared__ int cur[NCELL];
    __shared__ float rmnx[16], rmny[16], rmxx[16], rmxy[16];
    __shared__ float s_gp[4];
    __shared__ int bad;

    int lane = tid & 63, wid = tid >> 6;
    const float2* an2 = reinterpret_cast<const float2*>(anc);
    const float4* an4 = reinterpret_cast<const float4*>(anc);
    int aMain = A & ~4095;

    if (tid == 0) bad = 0;
    if (tid < NCELL) h[tid] = 0;
    __syncthreads();

    const unsigned int* mw = reinterpret_cast<const unsigned int*>(mask);
    int nw = nmask >> 2;
    for (int i = tid; i < nw; i += 1024) {
        unsigned int v = mw[i];
        if (v != 0u && v != 1u && v != 0x3f800000u) atomicOr(&bad, 1);
    }

    // pass 0: min/max (4 anchors/thread/iter)
    float mnx = 3e38f, mny = 3e38f, mxx = -3e38f, mxy = -3e38f;
    for (int base = 0; base < aMain; base += 4096) {
        int q = (base >> 1) + tid * 2;
        float4 p01 = an4[q], p23 = an4[q + 1];
        mnx = fminf(mnx, fminf(fminf(p01.x, p01.z), fminf(p23.x, p23.z)));
        mny = fminf(mny, fminf(fminf(p01.y, p01.w), fminf(p23.y, p23.w)));
        mxx = fmaxf(mxx, fmaxf(fmaxf(p01.x, p01.z), fmaxf(p23.x, p23.z)));
        mxy = fmaxf(mxy, fmaxf(fmaxf(p01.y, p01.w), fmaxf(p23.y, p23.w)));
    }
    for (int i = aMain + tid; i < A; i += 1024) {
        float2 p = an2[i];
        mnx = fminf(mnx, p.x); mny = fminf(mny, p.y);
        mxx = fmaxf(mxx, p.x); mxy = fmaxf(mxy, p.y);
    }
#pragma unroll
    for (int off = 32; off; off >>= 1) {
        mnx = fminf(mnx, __shfl_xor(mnx, off));
        mny = fminf(mny, __shfl_xor(mny, off));
        mxx = fmaxf(mxx, __shfl_xor(mxx, off));
        mxy = fmaxf(mxy, __shfl_xor(mxy, off));
    }
    if (lane == 0) { rmnx[wid] = mnx; rmny[wid] = mny; rmxx[wid] = mxx; rmxy[wid] = mxy; }
    __syncthreads();
    if (tid == 0) {
        mode[0] = bad ? 0 : 1;
        float a = 3e38f, b2 = 3e38f, c = -3e38f, d = -3e38f;
        for (int i = 0; i < 16; ++i) {
            a = fminf(a, rmnx[i]); b2 = fminf(b2, rmny[i]);
            c = fmaxf(c, rmxx[i]); d = fmaxf(d, rmxy[i]);
        }
        float rx = fmaxf(c - a, 1e-6f), ry = fmaxf(d - b2, 1e-6f);
        s_gp[0] = a; s_gp[1] = b2;
        s_gp[2] = (float)GX / rx; s_gp[3] = (float)GY / ry;
        gp[0] = s_gp[0]; gp[1] = s_gp[1]; gp[2] = s_gp[2]; gp[3] = s_gp[3];
    }
    __syncthreads();
    float ox = s_gp[0], oy = s_gp[1], ivx = s_gp[2], ivy = s_gp[3];

    // pass 1: histogram (4 anchors/thread/iter)
    for (int base = 0; base < aMain; base += 4096) {
        int q = (base >> 1) + tid * 2;
        float4 p01 = an4[q], p23 = an4[q + 1];
        { CELLOF(p01.x, p01.y, cx, cy) atomicAdd(&h[cy * GX + cx], 1); }
        { CELLOF(p01.z, p01.w, cx, cy) atomicAdd(&h[cy * GX + cx], 1); }
        { CELLOF(p23.x, p23.y, cx, cy) atomicAdd(&h[cy * GX + cx], 1); }
        { CELLOF(p23.z, p23.w, cx, cy) atomicAdd(&h[cy * GX + cx], 1); }
    }
    for (int i = aMain + tid; i < A; i += 1024) {
        float2 p = an2[i];
        CELLOF(p.x, p.y, cx, cy)
        atomicAdd(&h[cy * GX + cx], 1);
    }
    __syncthreads();
    if (wid == 0) {
        int base = 0;
        for (int ch = 0; ch < NCELL / 64; ++ch) {
            int v = h[ch * 64 + lane];
            int inc = v;
            for (int off = 1; off < 64; off <<= 1) {
                int u = __shfl_up(inc, off);
                if (lane >= off) inc += u;
            }
            cs[ch * 64 + lane] = base + inc - v;
            base += __shfl(inc, 63);
        }
        if (lane == 0) cs[NCELL] = base;
    }
    __syncthreads();
    if (tid <= NCELL) cell_start[tid] = cs[tid];
    if (tid < NCELL) cur[tid] = cs[tid];
    __syncthreads();
    // pass 2: scatter (4 anchors/thread/iter)
    for (int base = 0; base < aMain; base += 4096) {
        int a0 = base + tid * 4;
        int q = a0 >> 1;
        float4 p01 = an4[q], p23 = an4[q + 1];
        { CELLOF(p01.x, p01.y, cx, cy) binned[atomicAdd(&cur[cy * GX + cx], 1)] = a0; }
        { CELLOF(p01.z, p01.w, cx, cy) binned[atomicAdd(&cur[cy * GX + cx], 1)] = a0 + 1; }
        { CELLOF(p23.x, p23.y, cx, cy) binned[atomicAdd(&cur[cy * GX + cx], 1)] = a0 + 2; }
        { CELLOF(p23.z, p23.w, cx, cy) binned[atomicAdd(&cur[cy * GX + cx], 1)] = a0 + 3; }
    }
    for (int i = aMain + tid; i < A; i += 1024) {
        float2 p = an2[i];
        CELLOF(p.x, p.y, cx, cy)
        binned[atomicAdd(&cur[cy * GX + cx], 1)] = i;
    }
}

#define INTEST(ap) ((ap.x - x1a > EPS9) & (ap.y - y1a > EPS9) & \
                    (x2a - ap.x > EPS9) & (y2a - ap.y > EPS9))

// exact single-wave fallback scan (overflow path; dead for this input distribution)
__device__ void fb_scan(
    int lane, int A, int C, float x1a, float y1a, float x2a, float y2a,
    float w1h1, float atan1, int lbl,
    int cx0, int cx1, int cy0, int cy1,
    const float2* an2, const float4* pb4, const float* ps,
    const int* cell_start, const int* binned,
    int* count, int* win_idx, float* win_al, int* win_fl,
    size_t bA, int base_o)
{
    unsigned long long tv[NTOPK];
#pragma unroll
    for (int j = 0; j < NTOPK; ++j) tv[j] = 0;
    int pcnt = 0;
    for (int cy = cy0; cy <= cy1; ++cy) {
        int s = cell_start[cy * GX + cx0], e = cell_start[cy * GX + cx1 + 1];
        for (int i = s + lane; i < e; i += 64) {
            int a = binned[i];
            float2 ap = an2[a];
            bool in = INTEST(ap);
            if (in) {
                float4 pb = pb4[a];
                float w2 = pb.z - pb.x, h2 = pb.w - pb.y + EPSC;
                float at2 = atanf(w2 / h2);
                float ovl = ciou_clip(x1a, y1a, x2a, y2a, w1h1, atan1, pb, at2);
                float sc = (lbl >= 0) ? ps[(size_t)a * C + lbl] : 0.f;
                float o2 = ovl * ovl;
                float val = sqrtf(sc) * (o2 * o2 * o2);
                pcnt += (val > 0.f) ? 1 : 0;
                unsigned long long kk =
                    ((unsigned long long)__float_as_uint(val) << 32) | (unsigned)(~(unsigned)a);
                if (kk > tv[NTOPK - 1]) {
                    tv[NTOPK - 1] = kk;
#pragma unroll
                    for (int j = NTOPK - 1; j > 0; --j)
                        if (tv[j] > tv[j - 1]) {
                            unsigned long long t = tv[j]; tv[j] = tv[j - 1]; tv[j - 1] = t;
                        }
                }
            }
        }
    }
#pragma unroll
    for (int off = 32; off; off >>= 1) pcnt += __shfl_xor(pcnt, off);
    int rp = pcnt < NTOPK ? pcnt : NTOPK;
    for (int k = 0; k < rp; ++k) {
        unsigned long long head = tv[0];
        unsigned long long best = head;
#pragma unroll
        for (int off = 32; off; off >>= 1) {
            unsigned long long o = shfl_xor_u64(best, off);
            if (o > best) best = o;
        }
        if (head == best && head != 0ull) {
            int a = (int)(~(unsigned)(best & 0xFFFFFFFFull));
            int o = base_o + k;
            win_idx[o] = a; win_al[o] = __uint_as_float((unsigned)(best >> 32)); win_fl[o] = 1;
            atomicAdd(&count[bA + a], 1);
#pragma unroll
            for (int j = 0; j < NTOPK - 1; ++j) tv[j] = tv[j + 1];
            tv[NTOPK - 1] = 0;
        }
    }
    if (rp < NTOPK) {
        int iters = (A + 63 - lane) / 64;
        int zp = 0;
        for (int k = rp; k < NTOPK; ++k) {
            unsigned zprop = 0xFFFFFFFFu;
            while (zp < iters) {
                int a = lane + zp * 64;
                float2 ap = an2[a];
                if (!INTEST(ap)) { zprop = (unsigned)a; break; }
                ++zp;
            }
            unsigned cprop = 0xFFFFFFFFu;
#pragma unroll
            for (int j = 0; j < NTOPK; ++j) {
                unsigned long long kk = tv[j];
                if (kk != 0ull && kk < (1ull << 32)) {
                    unsigned idx2 = ~(unsigned)kk;
                    if (idx2 < cprop) cprop = idx2;
                }
            }
            unsigned prop = zprop < cprop ? zprop : cprop;
            unsigned bm_ = prop;
#pragma unroll
            for (int off = 32; off; off >>= 1) {
                unsigned o = (unsigned)__shfl_xor((int)bm_, off);
                if (o < bm_) bm_ = o;
            }
            if (bm_ != 0xFFFFFFFFu) {
                if (cprop == bm_ && cprop < zprop) {
                    int o = base_o + k;
                    win_idx[o] = (int)bm_; win_al[o] = 0.f; win_fl[o] = 1;
                    atomicAdd(&count[bA + bm_], 1);
                    unsigned long long wkk = (unsigned long long)(unsigned)(~bm_);
#pragma unroll
                    for (int j = 0; j < NTOPK; ++j) if (tv[j] == wkk) tv[j] = 0;
                } else if (zprop == bm_ && zprop < cprop) {
                    ++zp;
                }
            }
        }
    }
}

// K2: one 256-thread block per (b,m). Parallel strip-table setup; 4-wide batched
// predicated gathers; ballot-aggregated LDS pool; single-wave top-10 tournament
// == lax.top_k (value desc, idx asc) via u64 key (val_bits<<32)|~idx.
__global__ __launch_bounds__(256) void k_sel(
    const float* __restrict__ pd_scores, const float* __restrict__ pd_bboxes,
    const float* __restrict__ anc, const float* __restrict__ gt_labels,
    const float* __restrict__ gt_bboxes, const unsigned char* __restrict__ mask_gt,
    const int* __restrict__ mode, const int* __restrict__ cell_start,
    const int* __restrict__ binned, const float* __restrict__ gp,
    int* __restrict__ count, int* __restrict__ win_idx, float* __restrict__ win_al,
    int* __restrict__ win_fl,
    int A, int C, int M, int B)
{
    __shared__ unsigned long long pool[POOLCAP];
    __shared__ int sP[GY + 1];
    __shared__ int sB[GY];
    __shared__ int s_n, s_ovf;

    int rid = blockIdx.x;
    int b = rid % B, m = rid / B;        // XCD swizzle: same-b rows on one XCD (B%8==0)
    int row = b * M + m;
    if (!mask_at(mask_gt, row, mode[0])) return;   // win_fl pre-zeroed -> no claims
    int tid = threadIdx.x;
    int lane = tid & 63, wid = tid >> 6;

    float4 g = reinterpret_cast<const float4*>(gt_bboxes)[row];
    float x1a = g.x, y1a = g.y, x2a = g.z, y2a = g.w;
    float w1 = x2a - x1a, h1 = y2a - y1a + EPSC;
    float w1h1 = w1 * h1;
    float atan1 = atanf(w1 / h1);
    int lbl = (int)gt_labels[row];

    float ox = gp[0], oy = gp[1], ivx = gp[2], ivy = gp[3];
    // identical expressions to k_prep; monotone -> cannot miss any in-box anchor
    int cx0 = min(GX - 1, max(0, (int)floorf((x1a - ox) * ivx)));
    int cx1 = min(GX - 1, max(0, (int)floorf((x2a - ox) * ivx)));
    int cy0 = min(GY - 1, max(0, (int)floorf((y1a - oy) * ivy)));
    int cy1 = min(GY - 1, max(0, (int)floorf((y2a - oy) * ivy)));
    int ns = cy1 - cy0 + 1;

    // parallel strip table: 16-lane loads + shfl prefix
    if (wid == 0) {
        int len = 0, S = 0;
        if (lane < ns) {
            int cbase = (cy0 + lane) * GX;
            S = cell_start[cbase + cx0];
            len = cell_start[cbase + cx1 + 1] - S;
        }
        int inc = len;
#pragma unroll
        for (int off = 1; off < 16; off <<= 1) {
            int u = __shfl_up(inc, off);
            if (lane >= off) inc += u;
        }
        if (lane < ns) { sP[lane] = inc - len; sB[lane] = S - (inc - len); }
        if (lane == ns - 1) sP[ns] = inc;
        if (lane == 0) { s_n = 0; s_ovf = 0; }
    }
    __syncthreads();
    int L = sP[ns];

    const float2* an2 = reinterpret_cast<const float2*>(anc);
    const float4* pb4 = reinterpret_cast<const float4*>(pd_bboxes + (size_t)b * A * 4);
    const float*  ps  = pd_scores + (size_t)b * A * C;
    size_t bA = (size_t)b * A;
    int base_o = row * NTOPK;

    // Phase A: 4-wide batched candidate processing (predicated pb/ps gathers)
    int sptr = 0;
    for (int f0 = tid; f0 < L; f0 += 1024) {
        int f1 = f0 + 256, f2 = f0 + 512, f3 = f0 + 768;
        bool o1 = f1 < L, o2 = f2 < L, o3 = f3 < L;
        while (f0 >= sP[sptr + 1]) ++sptr;
        int sl0 = sB[sptr] + f0;
        int sp = sptr;
        if (o1) { while (f1 >= sP[sp + 1]) ++sp; }
        int sl1 = sB[sp] + f1;
        if (o2) { while (f2 >= sP[sp + 1]) ++sp; }
        int sl2 = sB[sp] + f2;
        if (o3) { while (f3 >= sP[sp + 1]) ++sp; }
        int sl3 = sB[sp] + f3;

        int a0 = binned[sl0];
        int a1 = o1 ? binned[sl1] : 0;
        int a2 = o2 ? binned[sl2] : 0;
        int a3 = o3 ? binned[sl3] : 0;
        float2 ap0 = an2[a0], ap1 = an2[a1], ap2 = an2[a2], ap3 = an2[a3];
        bool in0 = INTEST(ap0);
        bool in1 = o1 & INTEST(ap1);
        bool in2 = o2 & INTEST(ap2);
        bool in3 = o3 & INTEST(ap3);

        float4 pb0, pb1, pb2, pb3;
        float sc0 = 0.f, sc1 = 0.f, sc2 = 0.f, sc3 = 0.f;
        if (in0) { pb0 = pb4[a0]; if (lbl >= 0) sc0 = ps[(size_t)a0 * C + lbl]; }
        if (in1) { pb1 = pb4[a1]; if (lbl >= 0) sc1 = ps[(size_t)a1 * C + lbl]; }
        if (in2) { pb2 = pb4[a2]; if (lbl >= 0) sc2 = ps[(size_t)a2 * C + lbl]; }
        if (in3) { pb3 = pb4[a3]; if (lbl >= 0) sc3 = ps[(size_t)a3 * C + lbl]; }

#define PROC(ink, ak, pbk, sck) { \
        unsigned long long key = 0; \
        if (ink) { \
            float w2 = pbk.z - pbk.x, h2 = pbk.w - pbk.y + EPSC; \
            float at2 = atanf(w2 / h2); \
            float ovl = ciou_clip(x1a, y1a, x2a, y2a, w1h1, atan1, pbk, at2); \
            float o2v = ovl * ovl; \
            float val = sqrtf(sck) * (o2v * o2v * o2v); \
            key = ((unsigned long long)__float_as_uint(val) << 32) | (unsigned)(~(unsigned)ak); \
        } \
        unsigned long long ball = __ballot(ink); \
        if (ball) { \
            int bs = 0; \
            if (lane == 0) bs = atomicAdd(&s_n, __popcll(ball)); \
            bs = __shfl(bs, 0); \
            if (ink) { \
                int pos = bs + (int)lane_rank(ball); \
                if (pos < POOLCAP) pool[pos] = key; else s_ovf = 1; \
            } \
        } }
        PROC(in0, a0, pb0, sc0)
        PROC(in1, a1, pb1, sc1)
        PROC(in2, a2, pb2, sc2)
        PROC(in3, a3, pb3, sc3)
#undef PROC
    }
    __syncthreads();
    if (s_ovf || s_n > POOLCAP) {        // dead for this input (in-box <= ~1100 < 2048)
        if (wid == 0)
            fb_scan(lane, A, C, x1a, y1a, x2a, y2a, w1h1, atan1, lbl,
                    cx0, cx1, cy0, cy1, an2, pb4, ps, cell_start, binned,
                    count, win_idx, win_al, win_fl, bA, base_o);
        return;
    }
    if (wid != 0) return;                // Phase B is single-wave, barrier-free

    int n = s_n;
    unsigned long long tv[NTOPK];
#pragma unroll
    for (int j = 0; j < NTOPK; ++j) tv[j] = 0;
    int pcnt = 0;
    for (int i = lane; i < n; i += 64) {
        unsigned long long kk = pool[i];
        pcnt += (kk >> 32) ? 1 : 0;
        if (kk > tv[NTOPK - 1]) {
            tv[NTOPK - 1] = kk;
#pragma unroll
            for (int j = NTOPK - 1; j > 0; --j)
                if (tv[j] > tv[j - 1]) { unsigned long long t = tv[j]; tv[j] = tv[j - 1]; tv[j - 1] = t; }
        }
    }
#pragma unroll
    for (int off = 32; off; off >>= 1) pcnt += __shfl_xor(pcnt, off);
    int p = pcnt;
    int rp = p < NTOPK ? p : NTOPK;

    // 3a: positive rounds — register head + wave-max butterfly, winner pops
    for (int k = 0; k < rp; ++k) {
        unsigned long long head = tv[0];
        unsigned long long best = head;
#pragma unroll
        for (int off = 32; off; off >>= 1) {
            unsigned long long o = shfl_xor_u64(best, off);
            if (o > best) best = o;
        }
        if (head == best && head != 0ull) {      // unique owner (keys unique by idx)
            int a = (int)(~(unsigned)(best & 0xFFFFFFFFull));
            int o = base_o + k;
            win_idx[o] = a;
            win_al[o]  = __uint_as_float((unsigned)(best >> 32));
            win_fl[o]  = 1;
            atomicAdd(&count[bA + a], 1);
#pragma unroll
            for (int j = 0; j < NTOPK - 1; ++j) tv[j] = tv[j + 1];
            tv[NTOPK - 1] = 0;
        }
    }

    // 3b (rare: p < 10): fill with smallest-index zero-val anchors; in-box zero-vals claim.
    if (rp < NTOPK) {
        int iters = (A + 63 - lane) / 64;
        int zp = 0;
        for (int k = rp; k < NTOPK; ++k) {
            unsigned zprop = 0xFFFFFFFFu;
            while (zp < iters) {
                int a = lane + zp * 64;
                float2 ap = an2[a];
                if (!INTEST(ap)) { zprop = (unsigned)a; break; }
                ++zp;
            }
            unsigned cprop = 0xFFFFFFFFu;
#pragma unroll
            for (int j = 0; j < NTOPK; ++j) {
                unsigned long long kk = tv[j];
                if (kk != 0ull && kk < (1ull << 32)) {
                    unsigned idx2 = ~(unsigned)kk;
                    if (idx2 < cprop) cprop = idx2;
                }
            }
            unsigned prop = zprop < cprop ? zprop : cprop;
            unsigned bm_ = prop;
#pragma unroll
            for (int off = 32; off; off >>= 1) {
                unsigned o = (unsigned)__shfl_xor((int)bm_, off);
                if (o < bm_) bm_ = o;
            }
            if (bm_ != 0xFFFFFFFFu) {
                if (cprop == bm_ && cprop < zprop) {
                    int o = base_o + k;
                    win_idx[o] = (int)bm_; win_al[o] = 0.f; win_fl[o] = 1;
                    atomicAdd(&count[bA + bm_], 1);
                    unsigned long long wkk = (unsigned long long)(unsigned)(~bm_);
#pragma unroll
                    for (int j = 0; j < NTOPK; ++j) if (tv[j] == wkk) tv[j] = 0;
                } else if (zprop == bm_ && zprop < cprop) {
                    ++zp;
                }
            }
        }
    }
}

// K3: claim resolution + fused pos_al/pos_ov atomicMax (winner CIoU recomputed)
__global__ void k_resolve(
    const float* __restrict__ pd_scores, const float* __restrict__ pd_bboxes,
    const float* __restrict__ anc, const float* __restrict__ gt_labels,
    const float* __restrict__ gt_bboxes, const unsigned char* __restrict__ mask_gt,
    const int* __restrict__ mode,
    const int* __restrict__ count, const int* __restrict__ win_idx,
    const float* __restrict__ win_al, const int* __restrict__ win_fl,
    int* __restrict__ claim_m, float* __restrict__ claim_al,
    float* __restrict__ pos_al, float* __restrict__ pos_ov,
    int A, int C, int M, int total)
{
    int t = blockIdx.x * 256 + threadIdx.x;
    if (t >= total) return;
    int bm = t / NTOPK;
    int b = bm / M, m = bm % M;
    if (!win_fl[t]) return;
    int a = win_idx[t];
    size_t ba = (size_t)b * A + a;
    int cnt = count[ba];
    float al, ov; int mm_out;
    if (cnt == 1) {
        mm_out = m; al = win_al[t];
        float4 gg = reinterpret_cast<const float4*>(gt_bboxes)[b * M + m];
        float w1 = gg.z - gg.x, h1 = gg.w - gg.y + EPSC;
        float4 pb = reinterpret_cast<const float4*>(pd_bboxes)[ba];
        float w2 = pb.z - pb.x, h2p = pb.w - pb.y + EPSC;
        ov = ciou_clip(gg.x, gg.y, gg.z, gg.w, w1 * h1, atanf(w1 / h1), pb, atanf(w2 / h2p));
    } else {
        int wide = mode[0];
        float4 pb = reinterpret_cast<const float4*>(pd_bboxes)[ba];
        float2 ap = reinterpret_cast<const float2*>(anc)[a];
        float w2 = pb.z - pb.x, h2p = pb.w - pb.y + EPSC;
        float at2 = atanf(w2 / h2p);
        float best_ov = -1.f; int best_m = 0, best_valid = 0;
        for (int mm = 0; mm < M; ++mm) {
            float4 gg = reinterpret_cast<const float4*>(gt_bboxes)[b * M + mm];
            bool in = (ap.x - gg.x > EPS9) && (ap.y - gg.y > EPS9) &&
                      (gg.z - ap.x > EPS9) && (gg.w - ap.y > EPS9);
            bool valid = in && mask_at(mask_gt, b * M + mm, wide);
            float ovv = 0.f;
            if (valid) {
                float w1 = gg.z - gg.x, h1 = gg.w - gg.y + EPSC;
                ovv = ciou_clip(gg.x, gg.y, gg.z, gg.w, w1 * h1, atanf(w1 / h1), pb, at2);
            }
            if (ovv > best_ov) { best_ov = ovv; best_m = mm; best_valid = valid ? 1 : 0; }
        }
        int lb = (int)gt_labels[b * M + best_m];
        float sc = (best_valid && lb >= 0) ? pd_scores[ba * C + lb] : 0.f;
        float o2 = best_ov * best_ov;
        mm_out = best_m; al = sqrtf(sc) * (o2 * o2 * o2); ov = best_ov;
    }
    claim_m[ba]  = mm_out;
    claim_al[ba] = al;
    atomicMax((unsigned int*)&pos_al[b * M + mm_out], __float_as_uint(al));
    atomicMax((unsigned int*)&pos_ov[b * M + mm_out], __float_as_uint(ov));
}

// K4: per-anchor bb/fg + scattered single-score write (out_ts pre-zeroed)
__global__ __launch_bounds__(256) void k_final_small(
    const int* __restrict__ count, const int* __restrict__ claim_m,
    const float* __restrict__ claim_al,
    const float* __restrict__ pos_al, const float* __restrict__ pos_ov,
    const float* __restrict__ gt_labels, const float* __restrict__ gt_bboxes,
    float* __restrict__ out_bb, float* __restrict__ out_ts, float* __restrict__ out_fg,
    int A, int M, int C, int BA)
{
    int ba = blockIdx.x * 256 + threadIdx.x;
    if (ba >= BA) return;
    int b = ba / A;
    int cnt = count[ba];
    int m = (cnt > 0) ? claim_m[ba] : 0;       // background -> gt 0 (reference semantics)
    float4 g = reinterpret_cast<const float4*>(gt_bboxes)[b * M + m];
    reinterpret_cast<float4*>(out_bb)[ba] = g;
    out_fg[ba] = (cnt > 0) ? 1.f : 0.f;
    if (cnt > 0) {
        int lb = max((int)gt_labels[b * M + m], 0);
        float nv = claim_al[ba] * pos_ov[b * M + m] / (pos_al[b * M + m] + EPS9);
        out_ts[(size_t)ba * C + lb] = nv;      // sparse scatter (~15K total)
    }
}

extern "C" void kernel_launch(void* const* d_in, const int* in_sizes, int n_in,
                              void* d_out, int out_size, void* d_ws, size_t ws_size,
                              hipStream_t stream) {
    const float* pd_scores = (const float*)d_in[0];
    const float* pd_bboxes = (const float*)d_in[1];
    const float* anc       = (const float*)d_in[2];
    const float* gt_labels = (const float*)d_in[3];
    const float* gt_bboxes = (const float*)d_in[4];
    const unsigned char* mask_gt = (const unsigned char*)d_in[5];

    int A  = in_sizes[2] / 2;
    int BA = in_sizes[1] / 4;
    int B  = BA / A;
    int C  = in_sizes[0] / BA;
    int M  = in_sizes[3] / B;
    int BM = B * M;

    char* w = (char*)d_ws;
    auto alloc = [&](size_t bytes) { char* p = w; w += ((bytes + 255) / 256) * 256; return p; };
    int*   mode       = (int*)  alloc(256);
    char*  zero_beg   = w;
    int*   count      = (int*)  alloc((size_t)BA * 4);
    float* pos_al     = (float*)alloc((size_t)BM * 4);
    float* pos_ov     = (float*)alloc((size_t)BM * 4);
    int*   win_fl     = (int*)  alloc((size_t)BM * NTOPK * 4);
    char*  zero_end   = w;
    int*   claim_m    = (int*)  alloc((size_t)BA * 4);
    float* claim_al   = (float*)alloc((size_t)BA * 4);
    int*   win_idx    = (int*)  alloc((size_t)BM * NTOPK * 4);
    float* win_al     = (float*)alloc((size_t)BM * NTOPK * 4);
    int*   cell_start = (int*)  alloc((size_t)(NCELL + 1) * 4);
    int*   binned     = (int*)  alloc((size_t)A * 4);
    float* gp         = (float*)alloc(256);

    float* out_bb = (float*)d_out;
    float* out_ts = out_bb + (size_t)BA * 4;
    float* out_fg = out_ts + (size_t)BA * C;

    int n4ws = (int)((size_t)(zero_end - zero_beg) / 16);
    int n4ts = (int)((size_t)BA * C / 4);

    // fused: block 0 preps (mask detect + binning); blocks 1..512 zero ws + out_ts
    k_prep_zero<<<513, 1024, 0, stream>>>(mask_gt, BM, mode, anc, A, cell_start, binned, gp,
                                          (float4*)zero_beg, n4ws, (float4*)out_ts, n4ts);
    k_sel<<<BM, 256, 0, stream>>>(pd_scores, pd_bboxes, anc, gt_labels, gt_bboxes, mask_gt,
                                  mode, cell_start, binned, gp,
                                  count, win_idx, win_al, win_fl, A, C, M, B);
    int nclaims = BM * NTOPK;
    k_resolve<<<(nclaims + 255) / 256, 256, 0, stream>>>(
        pd_scores, pd_bboxes, anc, gt_labels, gt_bboxes, mask_gt, mode,
        count, win_idx, win_al, win_fl, claim_m, claim_al, pos_al, pos_ov, A, C, M, nclaims);
    int gBA = (BA + 255) / 256;
    k_final_small<<<gBA, 256, 0, stream>>>(count, claim_m, claim_al, pos_al, pos_ov,
                                           gt_labels, gt_bboxes, out_bb, out_ts, out_fg,
                                           A, M, C, BA);
}